// Round 3
// baseline (694.803 us; speedup 1.0000x reference)
//
#include <hip/hip_runtime.h>
#include <cstdint>
#include <cstddef>

typedef _Float16 f16;
typedef __attribute__((ext_vector_type(8))) _Float16 f16x8;
typedef __attribute__((ext_vector_type(4))) _Float16 f16x4;
typedef __attribute__((ext_vector_type(2))) _Float16 f16x2;
typedef __attribute__((ext_vector_type(4))) float f32x4;

#define MFMA_F16(a, b, c) __builtin_amdgcn_mfma_f32_16x16x32_f16((a), (b), (c), 0, 0, 0)

// ---------------------------------------------------------------------------
// k0: convert the three 512x512 fp32 weight matrices to f16 in workspace.
// ws layout (f16 elems): [0..262143]=W_left, [262144..524287]=W_right,
//                        [524288..786431]=W_out;  gp at byte offset 2MB (fast)
// ---------------------------------------------------------------------------
__global__ void k0_cvt(const float* __restrict__ wl, const float* __restrict__ wr,
                       const float* __restrict__ wo, f16* __restrict__ dst) {
    int i = blockIdx.x * 256 + threadIdx.x;
    dst[i]          = (f16)wl[i];
    dst[262144 + i] = (f16)wr[i];
    dst[524288 + i] = (f16)wo[i];
}

// ===========================================================================
// FAST PATH (requires ws_size >= 2MB + 128MB)
// ===========================================================================
// k1f: block 32 batches x 64 ch, 4 waves (2x2), wave tile 16x32, both sides.
// A (x fp32) staged->LDS f16 with 1-step prefetch; B direct global->reg,
// 2-deep. One barrier per K-step. gp written f16 to ws as [b][blade][ch].
// ---------------------------------------------------------------------------
__global__ __launch_bounds__(256, 2) void k1f(
    const float* __restrict__ x, const f16* __restrict__ wf,
    const float* __restrict__ bl_p, const float* __restrict__ br_p,
    f16* __restrict__ gp)
{
    __shared__ __align__(16) f16 As[2][8192];   // [buf][blade*1024 + row*32 + k] 32KB

    const int L = blockIdx.x;                   // 0..4095, XCD-chunked swizzle
    const int xcd = L & 7, sl = L >> 3;
    const int bt = xcd * 64 + (sl >> 3), ct = sl & 7;
    const int b0 = bt * 32, n0 = ct * 64;

    const int tid = threadIdx.x, lane = tid & 63, wv = tid >> 6;
    const int wb = wv >> 1, wn = wv & 1;
    const int r_lo = lane & 15, s_hi = lane >> 4;

    // --- A staging map: thread (sr=tid>>3, sq=tid&7): 32 consec f32 of row sr
    const int sr = tid >> 3, sq = tid & 7;
    const float* xsrc = x + (size_t)(b0 + sr) * 4096 + sq * 32;
    const int wbase = sr * 32 + ((((sq >> 1)) ^ (sr & 3)) << 3) + ((sq & 1) * 4);

    // --- B-frag pointers (side L/R x strip 0/1)
    const int nl0 = n0 + wn * 32 + r_lo;
    const f16* bp0 = wf + (size_t)nl0 * 512 + s_hi * 8;
    const f16* bp1 = wf + (size_t)(nl0 + 16) * 512 + s_hi * 8;
    const f16* bp2 = bp0 + 262144;
    const f16* bp3 = bp1 + 262144;

    const int ar = wb * 16 + r_lo;
    const int aoff = ar * 32 + ((s_hi ^ (ar & 3)) << 3);   // f16 idx in blade plane

    f32x4 accL[8][2], accR[8][2];
    const f32x4 zero = {0.f, 0.f, 0.f, 0.f};
#pragma unroll
    for (int i = 0; i < 8; ++i) { accL[i][0]=zero; accL[i][1]=zero; accR[i][0]=zero; accR[i][1]=zero; }

    // prologue: A(0) -> buf0, B(0) -> bcur
    f16x8 bcur0 = *(const f16x8*)bp0, bcur1 = *(const f16x8*)bp1;
    f16x8 bcur2 = *(const f16x8*)bp2, bcur3 = *(const f16x8*)bp3;
    {
        f32x4 xa[8];
#pragma unroll
        for (int u = 0; u < 8; ++u) xa[u] = *(const f32x4*)(xsrc + u * 4);
#pragma unroll
        for (int i = 0; i < 8; ++i) {
            f16x4 w;
#pragma unroll
            for (int dm = 0; dm < 4; ++dm) w[dm] = (f16)xa[dm * 2 + (i >> 2)][i & 3];
            *(f16x4*)&As[0][i * 1024 + wbase] = w;
        }
    }
    __syncthreads();

#pragma unroll
    for (int kk = 0; kk < 16; ++kk) {
        const int buf = kk & 1;
        f16x8 bn0, bn1, bn2, bn3;
        f32x4 xn[8];
        if (kk < 15) {
            bn0 = *(const f16x8*)(bp0 + (kk + 1) * 32);
            bn1 = *(const f16x8*)(bp1 + (kk + 1) * 32);
            bn2 = *(const f16x8*)(bp2 + (kk + 1) * 32);
            bn3 = *(const f16x8*)(bp3 + (kk + 1) * 32);
#pragma unroll
            for (int u = 0; u < 8; ++u) xn[u] = *(const f32x4*)(xsrc + (kk + 1) * 256 + u * 4);
        }
#pragma unroll
        for (int i = 0; i < 8; ++i) {
            f16x8 a = *(const f16x8*)&As[buf][i * 1024 + aoff];
            accL[i][0] = MFMA_F16(a, bcur0, accL[i][0]);
            accL[i][1] = MFMA_F16(a, bcur1, accL[i][1]);
            accR[i][0] = MFMA_F16(a, bcur2, accR[i][0]);
            accR[i][1] = MFMA_F16(a, bcur3, accR[i][1]);
        }
        if (kk < 15) {
#pragma unroll
            for (int i = 0; i < 8; ++i) {
                f16x4 w;
#pragma unroll
                for (int dm = 0; dm < 4; ++dm) w[dm] = (f16)xn[dm * 2 + (i >> 2)][i & 3];
                *(f16x4*)&As[buf ^ 1][i * 1024 + wbase] = w;
            }
            bcur0 = bn0; bcur1 = bn1; bcur2 = bn2; bcur3 = bn3;
        }
        __syncthreads();
    }

    // epilogue: bias + geometric product, store gp f16 to ws [b][blade][ch]
#pragma unroll
    for (int t = 0; t < 2; ++t) {
        const int n_g = n0 + wn * 32 + t * 16 + r_lo;
        const float blv = bl_p[n_g], brv = br_p[n_g];
#pragma unroll
        for (int rr = 0; rr < 4; ++rr) {
            const int b_g = b0 + wb * 16 + s_hi * 4 + rr;
            float Lv[8], Rv[8];
#pragma unroll
            for (int i = 0; i < 8; ++i) { Lv[i] = accL[i][t][rr]; Rv[i] = accR[i][t][rr]; }
            Lv[0] += blv; Rv[0] += brv;
            float g[8];
            g[0] = Lv[0]*Rv[0]+Lv[1]*Rv[1]+Lv[2]*Rv[2]+Lv[3]*Rv[3]-Lv[4]*Rv[4]-Lv[5]*Rv[5]-Lv[6]*Rv[6]-Lv[7]*Rv[7];
            g[1] = Lv[0]*Rv[1]+Lv[1]*Rv[0]-Lv[2]*Rv[4]-Lv[3]*Rv[5]+Lv[4]*Rv[2]+Lv[5]*Rv[3]-Lv[6]*Rv[7]-Lv[7]*Rv[6];
            g[2] = Lv[0]*Rv[2]+Lv[1]*Rv[4]+Lv[2]*Rv[0]-Lv[3]*Rv[6]-Lv[4]*Rv[1]+Lv[5]*Rv[7]+Lv[6]*Rv[3]+Lv[7]*Rv[5];
            g[3] = Lv[0]*Rv[3]+Lv[1]*Rv[5]+Lv[2]*Rv[6]+Lv[3]*Rv[0]-Lv[4]*Rv[7]-Lv[5]*Rv[1]-Lv[6]*Rv[2]-Lv[7]*Rv[4];
            g[4] = Lv[0]*Rv[4]+Lv[1]*Rv[2]-Lv[2]*Rv[1]+Lv[3]*Rv[7]+Lv[4]*Rv[0]-Lv[5]*Rv[6]+Lv[6]*Rv[5]+Lv[7]*Rv[3];
            g[5] = Lv[0]*Rv[5]+Lv[1]*Rv[3]-Lv[2]*Rv[7]-Lv[3]*Rv[1]+Lv[4]*Rv[6]+Lv[5]*Rv[0]-Lv[6]*Rv[4]-Lv[7]*Rv[2];
            g[6] = Lv[0]*Rv[6]+Lv[1]*Rv[7]+Lv[2]*Rv[3]-Lv[3]*Rv[2]-Lv[4]*Rv[5]+Lv[5]*Rv[4]+Lv[6]*Rv[0]+Lv[7]*Rv[1];
            g[7] = Lv[0]*Rv[7]+Lv[1]*Rv[6]-Lv[2]*Rv[5]+Lv[3]*Rv[4]+Lv[4]*Rv[3]-Lv[5]*Rv[2]+Lv[6]*Rv[1]+Lv[7]*Rv[0];
            f16* dst = gp + (size_t)b_g * 4096 + n_g;
#pragma unroll
            for (int i = 0; i < 8; ++i) dst[i * 512] = (f16)g[i];
        }
    }
}

// ---------------------------------------------------------------------------
// k2f: barrier-free GEMM. Block 16 batches x 512 ch, 8 waves, wave 16x64.
// A-frags direct global from gp(ws) [b][blade][ch]; B-frags direct from W_out.
// 2-deep register pipeline; one barrier only for the norm reduction; writes
// d_out (disjoint from ws) -> no hazard.
// ---------------------------------------------------------------------------
__global__ __launch_bounds__(512, 2) void k2f(
    const f16* __restrict__ gp, const f16* __restrict__ wo,
    const float* __restrict__ bo_p, const float* __restrict__ an_p,
    float* __restrict__ outp)
{
    __shared__ float red[16][8];

    const int b0 = blockIdx.x * 16;
    const int tid = threadIdx.x, lane = tid & 63, wv = tid >> 6;   // wv 0..7
    const int r_lo = lane & 15, s_hi = lane >> 4;

    // A: row = batch r_lo, blade i, k = ch
    const f16* ap0 = gp + (size_t)(b0 + r_lo) * 4096 + s_hi * 8;       // blades 0..3: +i*512
    const f16* ap1 = ap0 + 2048;                                       // blades 4..7
    // B: 4 strips
    const f16* bq0 = wo + (size_t)(wv * 64 + r_lo) * 512 + s_hi * 8;
    const f16* bq1 = bq0 + 16 * 512;
    const f16* bq2 = bq0 + 32 * 512;
    const f16* bq3 = bq0 + 48 * 512;

    f32x4 acc[8][4];
    const f32x4 zero = {0.f, 0.f, 0.f, 0.f};
#pragma unroll
    for (int i = 0; i < 8; ++i)
#pragma unroll
        for (int t = 0; t < 4; ++t) acc[i][t] = zero;

    f16x8 aA[8], bB[4];
#pragma unroll
    for (int i = 0; i < 4; ++i) {
        aA[i]     = *(const f16x8*)(ap0 + i * 512);
        aA[i + 4] = *(const f16x8*)(ap1 + i * 512);
    }
    bB[0] = *(const f16x8*)bq0; bB[1] = *(const f16x8*)bq1;
    bB[2] = *(const f16x8*)bq2; bB[3] = *(const f16x8*)bq3;

#pragma unroll
    for (int kk = 0; kk < 16; ++kk) {
        f16x8 aN[8], bN[4];
        if (kk < 15) {
            const int o = (kk + 1) * 32;
#pragma unroll
            for (int i = 0; i < 4; ++i) {
                aN[i]     = *(const f16x8*)(ap0 + i * 512 + o);
                aN[i + 4] = *(const f16x8*)(ap1 + i * 512 + o);
            }
            bN[0] = *(const f16x8*)(bq0 + o); bN[1] = *(const f16x8*)(bq1 + o);
            bN[2] = *(const f16x8*)(bq2 + o); bN[3] = *(const f16x8*)(bq3 + o);
        }
#pragma unroll
        for (int i = 0; i < 8; ++i) {
            acc[i][0] = MFMA_F16(aA[i], bB[0], acc[i][0]);
            acc[i][1] = MFMA_F16(aA[i], bB[1], acc[i][1]);
            acc[i][2] = MFMA_F16(aA[i], bB[2], acc[i][2]);
            acc[i][3] = MFMA_F16(aA[i], bB[3], acc[i][3]);
        }
        if (kk < 15) {
#pragma unroll
            for (int i = 0; i < 8; ++i) aA[i] = aN[i];
#pragma unroll
            for (int t = 0; t < 4; ++t) bB[t] = bN[t];
        }
    }

    float bo_t[4], an_t[4];
#pragma unroll
    for (int t = 0; t < 4; ++t) {
        const int c = wv * 64 + t * 16 + r_lo;
        bo_t[t] = bo_p[c]; an_t[t] = an_p[c];
    }

    float partial[4];
#pragma unroll
    for (int rr = 0; rr < 4; ++rr) {
        float sum = 0.f;
#pragma unroll
        for (int t = 0; t < 4; ++t) {
            float o = acc[0][t][rr] + bo_t[t];
            float ss = o * o;
#pragma unroll
            for (int i = 1; i < 8; ++i) ss += acc[i][t][rr] * acc[i][t][rr];
            sum += sqrtf(ss);
        }
        partial[rr] = sum;
    }
#pragma unroll
    for (int off = 1; off < 16; off <<= 1)
#pragma unroll
        for (int rr = 0; rr < 4; ++rr) partial[rr] += __shfl_xor(partial[rr], off);
    if (r_lo == 0)
#pragma unroll
        for (int rr = 0; rr < 4; ++rr) red[s_hi * 4 + rr][wv] = partial[rr];
    __syncthreads();

#pragma unroll
    for (int rr = 0; rr < 4; ++rr) {
        float tot = 0.f;
#pragma unroll
        for (int w = 0; w < 8; ++w) tot += red[s_hi * 4 + rr][w];
        const float inv = 1.0f / (tot * (1.0f / 512.0f) + 1e-6f);
        const int b_g = b0 + s_hi * 4 + rr;
        float* dst = outp + (size_t)b_g * 4096;
#pragma unroll
        for (int t = 0; t < 4; ++t) {
            const float sc = an_t[t] * inv;
            const int c = wv * 64 + t * 16 + r_lo;
            f32x4 v0, v1;
            v0[0] = (acc[0][t][rr] + bo_t[t]) * sc;
            v0[1] = acc[1][t][rr] * sc; v0[2] = acc[2][t][rr] * sc; v0[3] = acc[3][t][rr] * sc;
            v1[0] = acc[4][t][rr] * sc; v1[1] = acc[5][t][rr] * sc;
            v1[2] = acc[6][t][rr] * sc; v1[3] = acc[7][t][rr] * sc;
            *(f32x4*)(dst + (size_t)c * 8) = v0;
            *(f32x4*)(dst + (size_t)c * 8 + 4) = v1;
        }
    }
}

// ===========================================================================
// FALLBACK PATH (ws too small) — the round-2 passing kernels, verbatim.
// ===========================================================================
__global__ __launch_bounds__(512, 4) void k1_gp(
    const float* __restrict__ x, const f16* __restrict__ wf,
    const float* __restrict__ bl_p, const float* __restrict__ br_p,
    char* gp_out)
{
    __shared__ __align__(16) f16 As[2][8][32*32];
    __shared__ __align__(16) f16 Ws[2][2][64*32];

    const int L   = blockIdx.x;
    const int xcd = L & 7, sl = L >> 3;
    const int bt  = xcd * 64 + (sl >> 3);
    const int ct  = sl & 7;
    const int b0  = bt * 32;
    const int n0  = ct * 64;

    const int tid  = threadIdx.x;
    const int lane = tid & 63;
    const int wv   = tid >> 6;
    const int wb   = wv >> 2, wn = wv & 3;
    const int r_lo = lane & 15, s_hi = lane >> 4;

    f32x4 accL[8], accR[8];
    const f32x4 zero = {0.f, 0.f, 0.f, 0.f};
#pragma unroll
    for (int i = 0; i < 8; ++i) { accL[i] = zero; accR[i] = zero; }

    const int sbb = tid >> 4, smg = tid & 15;
    const int abase = sbb * 32 + (((smg >> 2) ^ (sbb & 3)) << 3) + ((2 * smg) & 7);
    const int wside = tid >> 8, wnl = (tid >> 2) & 63, wc = tid & 3;
    const int wbase = wnl * 32 + ((wc ^ (wnl & 3)) << 3);
    const float* xsrc0 = x + ((size_t)(b0 + sbb) * 512 + 2 * smg) * 8;
    const f16*   wsrc0 = wf + (size_t)wside * (512 * 512) + (size_t)(n0 + wnl) * 512 + wc * 8;

    auto stage = [&](int kk, int buf) {
        const float* src = xsrc0 + (size_t)kk * 256;
        f32x4 a0 = *(const f32x4*)(src);
        f32x4 a1 = *(const f32x4*)(src + 4);
        f32x4 a2 = *(const f32x4*)(src + 8);
        f32x4 a3 = *(const f32x4*)(src + 12);
#pragma unroll
        for (int i = 0; i < 4; ++i) {
            f16x2 p; p[0] = (f16)a0[i]; p[1] = (f16)a2[i];
            *(f16x2*)&As[buf][i][abase] = p;
            f16x2 q; q[0] = (f16)a1[i]; q[1] = (f16)a3[i];
            *(f16x2*)&As[buf][i + 4][abase] = q;
        }
        f16x8 w8 = *(const f16x8*)(wsrc0 + kk * 32);
        *(f16x8*)&Ws[buf][wside][wbase] = w8;
    };

    const int ar   = wb * 16 + r_lo;
    const int aoff = ar * 32 + ((s_hi ^ (ar & 3)) << 3);
    const int nloc = wn * 16 + r_lo;
    const int boff = nloc * 32 + ((s_hi ^ (nloc & 3)) << 3);

    stage(0, 0);
    for (int kk = 0; kk < 16; ++kk) {
        __syncthreads();
        if (kk < 15) stage(kk + 1, (kk + 1) & 1);
        const int buf = kk & 1;
        f16x8 bL = *(const f16x8*)&Ws[buf][0][boff];
        f16x8 bR = *(const f16x8*)&Ws[buf][1][boff];
#pragma unroll
        for (int i = 0; i < 8; ++i) {
            f16x8 a = *(const f16x8*)&As[buf][i][aoff];
            accL[i] = MFMA_F16(a, bL, accL[i]);
            accR[i] = MFMA_F16(a, bR, accR[i]);
        }
    }

    const int n_g = n0 + nloc;
    const float blv = bl_p[n_g], brv = br_p[n_g];
#pragma unroll
    for (int rr = 0; rr < 4; ++rr) {
        const int b_g = b0 + wb * 16 + s_hi * 4 + rr;
        float Lv[8], Rv[8];
#pragma unroll
        for (int i = 0; i < 8; ++i) { Lv[i] = accL[i][rr]; Rv[i] = accR[i][rr]; }
        Lv[0] += blv; Rv[0] += brv;
        float g[8];
        g[0] = Lv[0]*Rv[0]+Lv[1]*Rv[1]+Lv[2]*Rv[2]+Lv[3]*Rv[3]-Lv[4]*Rv[4]-Lv[5]*Rv[5]-Lv[6]*Rv[6]-Lv[7]*Rv[7];
        g[1] = Lv[0]*Rv[1]+Lv[1]*Rv[0]-Lv[2]*Rv[4]-Lv[3]*Rv[5]+Lv[4]*Rv[2]+Lv[5]*Rv[3]-Lv[6]*Rv[7]-Lv[7]*Rv[6];
        g[2] = Lv[0]*Rv[2]+Lv[1]*Rv[4]+Lv[2]*Rv[0]-Lv[3]*Rv[6]-Lv[4]*Rv[1]+Lv[5]*Rv[7]+Lv[6]*Rv[3]+Lv[7]*Rv[5];
        g[3] = Lv[0]*Rv[3]+Lv[1]*Rv[5]+Lv[2]*Rv[6]+Lv[3]*Rv[0]-Lv[4]*Rv[7]-Lv[5]*Rv[1]-Lv[6]*Rv[2]-Lv[7]*Rv[4];
        g[4] = Lv[0]*Rv[4]+Lv[1]*Rv[2]-Lv[2]*Rv[1]+Lv[3]*Rv[7]+Lv[4]*Rv[0]-Lv[5]*Rv[6]+Lv[6]*Rv[5]+Lv[7]*Rv[3];
        g[5] = Lv[0]*Rv[5]+Lv[1]*Rv[3]-Lv[2]*Rv[7]-Lv[3]*Rv[1]+Lv[4]*Rv[6]+Lv[5]*Rv[0]-Lv[6]*Rv[4]-Lv[7]*Rv[2];
        g[6] = Lv[0]*Rv[6]+Lv[1]*Rv[7]+Lv[2]*Rv[3]-Lv[3]*Rv[2]-Lv[4]*Rv[5]+Lv[5]*Rv[4]+Lv[6]*Rv[0]+Lv[7]*Rv[1];
        g[7] = Lv[0]*Rv[7]+Lv[1]*Rv[6]-Lv[2]*Rv[5]+Lv[3]*Rv[4]+Lv[4]*Rv[3]-Lv[5]*Rv[2]+Lv[6]*Rv[1]+Lv[7]*Rv[0];
        char* dst = gp_out + (size_t)b_g * 16384 + (size_t)n_g * 2;
#pragma unroll
        for (int i = 0; i < 8; ++i) *(f16*)(dst + (size_t)i * 1024) = (f16)g[i];
    }
}

__global__ __launch_bounds__(1024, 4) void k2_out(
    const char* gp_in, const f16* __restrict__ wo,
    const float* __restrict__ bo_p, const float* __restrict__ an_p,
    float* outp)
{
    __shared__ __align__(16) f16 As[2][8][16*32];
    __shared__ __align__(16) f16 Bs[2][512*32];
    __shared__ float red[16][16];

    const int b0   = blockIdx.x * 16;
    const int tid  = threadIdx.x;
    const int lane = tid & 63;
    const int wv   = tid >> 6;
    const int r_lo = lane & 15, s_hi = lane >> 4;

    f32x4 acc[2][8];
    const f32x4 zero = {0.f, 0.f, 0.f, 0.f};
#pragma unroll
    for (int st = 0; st < 2; ++st)
#pragma unroll
        for (int i = 0; i < 8; ++i) acc[st][i] = zero;

    const int ablade = tid >> 6, arow = (tid >> 2) & 15, ac = tid & 3;
    const char* asrc0 = gp_in + (size_t)(b0 + arow) * 16384 + ablade * 1024 + ac * 16;
    const int aw = arow * 32 + ((ac ^ (arow & 3)) << 3);
    const int brow = tid >> 1, bc2 = (tid & 1) * 2;
    const f16* bsrc0 = wo + (size_t)brow * 512 + bc2 * 8;
    const int bw0 = brow * 32 + (((bc2    ) ^ (brow & 3)) << 3);
    const int bw1 = brow * 32 + (((bc2 + 1) ^ (brow & 3)) << 3);

    auto stage = [&](int kk, int buf) {
        if (tid < 512) {
            f16x8 v = *(const f16x8*)(asrc0 + (size_t)kk * 64);
            *(f16x8*)&As[buf][ablade][aw] = v;
        }
        const f16* bs = bsrc0 + kk * 32;
        f16x8 v0 = *(const f16x8*)(bs);
        f16x8 v1 = *(const f16x8*)(bs + 8);
        *(f16x8*)&Bs[buf][bw0] = v0;
        *(f16x8*)&Bs[buf][bw1] = v1;
    };

    const int nl0 = wv * 32 + r_lo, nl1 = nl0 + 16;
    const int boff0 = nl0 * 32 + ((s_hi ^ (nl0 & 3)) << 3);
    const int boff1 = nl1 * 32 + ((s_hi ^ (nl1 & 3)) << 3);
    const int aoff  = r_lo * 32 + ((s_hi ^ (r_lo & 3)) << 3);

    stage(0, 0);
    for (int kk = 0; kk < 16; ++kk) {
        __syncthreads();
        if (kk < 15) stage(kk + 1, (kk + 1) & 1);
        const int buf = kk & 1;
        f16x8 bf0 = *(const f16x8*)&Bs[buf][boff0];
        f16x8 bf1 = *(const f16x8*)&Bs[buf][boff1];
#pragma unroll
        for (int i = 0; i < 8; ++i) {
            f16x8 a = *(const f16x8*)&As[buf][i][aoff];
            acc[0][i] = MFMA_F16(a, bf0, acc[0][i]);
            acc[1][i] = MFMA_F16(a, bf1, acc[1][i]);
        }
    }

    const float bo0 = bo_p[nl0], bo1 = bo_p[nl1];
    const float an0 = an_p[nl0], an1 = an_p[nl1];

    float partial[4];
#pragma unroll
    for (int rr = 0; rr < 4; ++rr) {
        float o = acc[0][0][rr] + bo0;
        float ss = o * o;
#pragma unroll
        for (int i = 1; i < 8; ++i) ss += acc[0][i][rr] * acc[0][i][rr];
        float s = sqrtf(ss);
        o = acc[1][0][rr] + bo1;
        ss = o * o;
#pragma unroll
        for (int i = 1; i < 8; ++i) ss += acc[1][i][rr] * acc[1][i][rr];
        partial[rr] = s + sqrtf(ss);
    }
#pragma unroll
    for (int off = 1; off < 16; off <<= 1) {
#pragma unroll
        for (int rr = 0; rr < 4; ++rr) partial[rr] += __shfl_xor(partial[rr], off);
    }
    if (r_lo == 0) {
#pragma unroll
        for (int rr = 0; rr < 4; ++rr) red[s_hi * 4 + rr][wv] = partial[rr];
    }
    __syncthreads();

#pragma unroll
    for (int rr = 0; rr < 4; ++rr) {
        float tot = 0.f;
#pragma unroll
        for (int w = 0; w < 16; ++w) tot += red[s_hi * 4 + rr][w];
        const float inv = 1.0f / (tot * (1.0f / 512.0f) + 1e-6f);
        const float sc0 = an0 * inv, sc1 = an1 * inv;
        const int b_g = b0 + s_hi * 4 + rr;
        float* dst = outp + (size_t)b_g * 4096;
        f32x4 v;
        v[0] = (acc[0][0][rr] + bo0) * sc0;
        v[1] = acc[0][1][rr] * sc0;
        v[2] = acc[0][2][rr] * sc0;
        v[3] = acc[0][3][rr] * sc0;
        *(f32x4*)(dst + (size_t)nl0 * 8) = v;
        v[0] = acc[0][4][rr] * sc0;
        v[1] = acc[0][5][rr] * sc0;
        v[2] = acc[0][6][rr] * sc0;
        v[3] = acc[0][7][rr] * sc0;
        *(f32x4*)(dst + (size_t)nl0 * 8 + 4) = v;
        v[0] = (acc[1][0][rr] + bo1) * sc1;
        v[1] = acc[1][1][rr] * sc1;
        v[2] = acc[1][2][rr] * sc1;
        v[3] = acc[1][3][rr] * sc1;
        *(f32x4*)(dst + (size_t)nl1 * 8) = v;
        v[0] = acc[1][4][rr] * sc1;
        v[1] = acc[1][5][rr] * sc1;
        v[2] = acc[1][6][rr] * sc1;
        v[3] = acc[1][7][rr] * sc1;
        *(f32x4*)(dst + (size_t)nl1 * 8 + 4) = v;
    }
}

// ---------------------------------------------------------------------------
extern "C" void kernel_launch(void* const* d_in, const int* in_sizes, int n_in,
                              void* d_out, int out_size, void* d_ws, size_t ws_size,
                              hipStream_t stream) {
    const float* x  = (const float*)d_in[0];
    const float* wl = (const float*)d_in[1];
    const float* bl = (const float*)d_in[2];
    const float* wr = (const float*)d_in[3];
    const float* br = (const float*)d_in[4];
    const float* wo = (const float*)d_in[5];
    const float* bo = (const float*)d_in[6];
    const float* an = (const float*)d_in[7];
    f16* wf = (f16*)d_ws;

    hipLaunchKernelGGL(k0_cvt, dim3(1024), dim3(256), 0, stream, wl, wr, wo, wf);

    const size_t need = (size_t)2 * 1024 * 1024 + (size_t)16384 * 8192;  // 2MB + 128MB
    if (ws_size >= need) {
        f16* gp = wf + (1 << 20);   // byte offset 2MB
        hipLaunchKernelGGL(k1f, dim3(4096), dim3(256), 0, stream, x, wf, bl, br, gp);
        hipLaunchKernelGGL(k2f, dim3(1024), dim3(512), 0, stream,
                           gp, wf + 524288, bo, an, (float*)d_out);
    } else {
        hipLaunchKernelGGL(k1_gp, dim3(4096), dim3(512), 0, stream, x, wf, bl, br, (char*)d_out);
        hipLaunchKernelGGL(k2_out, dim3(1024), dim3(1024), 0, stream,
                           (const char*)d_out, wf + 524288, bo, an, (float*)d_out);
    }
}

// Round 4
// 453.395 us; speedup vs baseline: 1.5324x; 1.5324x over previous
//
#include <hip/hip_runtime.h>
#include <cstdint>
#include <cstddef>

typedef _Float16 f16;
typedef __attribute__((ext_vector_type(8))) _Float16 f16x8;
typedef __attribute__((ext_vector_type(4))) _Float16 f16x4;
typedef __attribute__((ext_vector_type(4))) float f32x4;

#define MFMA_F16(a, b, c) __builtin_amdgcn_mfma_f32_16x16x32_f16((a), (b), (c), 0, 0, 0)

// global -> LDS direct, 16B per lane. LDS dest must be the WAVE base
// (HW adds lane*16); global src is per-lane.
#define GL2LDS(gsrc, ldst)                                                  \
    __builtin_amdgcn_global_load_lds(                                        \
        (const __attribute__((address_space(1))) void*)(gsrc),               \
        (__attribute__((address_space(3))) void*)(ldst), 16, 0, 0)

// ws layout (f16 elems): [0,262144) W_L | [262144,524288) W_R |
//   [524288,786432) W_out | xt (x transposed f16) at elem 1<<20 (byte 2MB),
//   8 blade planes of 16384x512, plane stride 8388608 elems.
// gp (f16) lives in d_out: batch b at byte b*16384, blade i at +i*1024, ch n at +2n.

// ---------------------------------------------------------------------------
// k0w: weights fp32 -> f16
// ---------------------------------------------------------------------------
__global__ void k0w(const float* __restrict__ wl, const float* __restrict__ wr,
                    const float* __restrict__ wo, f16* __restrict__ dst) {
    int i = blockIdx.x * 256 + threadIdx.x;
    dst[i]          = (f16)wl[i];
    dst[262144 + i] = (f16)wr[i];
    dst[524288 + i] = (f16)wo[i];
}

// ---------------------------------------------------------------------------
// k0x: x [b][m][blade] fp32  ->  xt [blade][b][m] f16.
// Block 256 thr: 4 batches x 256 m. Reads 128B/lane coalesced; writes 8B/lane,
// 512B contiguous per wave per blade.
// ---------------------------------------------------------------------------
__global__ __launch_bounds__(256) void k0x(const float* __restrict__ x,
                                           f16* __restrict__ xt) {
    const int bid = blockIdx.x;                 // 0..8191
    const int b   = (bid >> 1) * 4 + (threadIdx.x >> 6);
    const int m   = (bid & 1) * 256 + (threadIdx.x & 63) * 4;
    const float* src = x + ((size_t)b * 512 + m) * 8;   // 32 consecutive floats
    f32x4 v[8];
#pragma unroll
    for (int u = 0; u < 8; ++u) v[u] = *(const f32x4*)(src + u * 4);
#pragma unroll
    for (int i = 0; i < 8; ++i) {
        f16x4 w;
#pragma unroll
        for (int j = 0; j < 4; ++j) w[j] = (f16)v[j * 2 + (i >> 2)][i & 3];
        *(f16x4*)(xt + (size_t)i * 8388608 + (size_t)b * 512 + m) = w;
    }
}

// ---------------------------------------------------------------------------
// k1: vec_L/vec_R GEMMs + geometric product. Block 32 b x 64 ch, BK=32,
// 8 waves (16x16, L+R). ALL staging via global_load_lds(16B), sources
// pre-swizzled so the LDS image is identical to the round-2 kernel.
// ---------------------------------------------------------------------------
__global__ __launch_bounds__(512, 4) void k1(
    const f16* __restrict__ xt, const f16* __restrict__ wf,
    const float* __restrict__ bl_p, const float* __restrict__ br_p,
    char* gp_out)
{
    __shared__ __align__(16) f16 AsF[2 * 8192];   // [buf][blade][row32][k32] 32KB
    __shared__ __align__(16) f16 WsF[2 * 4096];   // [buf][side][n64][k32]    16KB

    const int L = blockIdx.x;                     // XCD-chunked swizzle
    const int xcd = L & 7, sl = L >> 3;
    const int bt = xcd * 64 + (sl >> 3), ct = sl & 7;
    const int b0 = bt * 32, n0 = ct * 64;

    const int tid = threadIdx.x, lane = tid & 63, wv = tid >> 6;
    const int wb = wv >> 2, wn = wv & 3;
    const int r_lo = lane & 15, s_hi = lane >> 4;

    // --- staging sources (per lane, swizzle baked into source k-group) ---
    // A call j covers flat groups g = j*512 + tid; g -> (blade, row, grp)
    const int gA0 = tid, gA1 = tid + 512;
    const int ba0 = gA0 >> 7, ra0 = (gA0 >> 2) & 31, ga0 = (gA0 & 3) ^ (ra0 & 3);
    const int ba1 = gA1 >> 7, ra1 = (gA1 >> 2) & 31, ga1 = (gA1 & 3) ^ (ra1 & 3);
    const f16* aS0 = xt + (size_t)ba0 * 8388608 + (size_t)(b0 + ra0) * 512 + ga0 * 8;
    const f16* aS1 = xt + (size_t)ba1 * 8388608 + (size_t)(b0 + ra1) * 512 + ga1 * 8;
    // W: g = tid -> (side, n, grp)
    const int side = tid >> 8, wn_ = (tid >> 2) & 63, wg = (tid & 3) ^ (wn_ & 3);
    const f16* wS = wf + (size_t)side * 262144 + (size_t)(n0 + wn_) * 512 + wg * 8;

    // wave-uniform LDS dest bases (lane*16B added by HW)
    f16* aD0 = AsF + wv * 512;
    f16* aD1 = AsF + 4096 + wv * 512;
    f16* wD  = WsF + wv * 512;

    // --- compute-side LDS offsets (identical image to round-2) ---
    const int ar = wb * 16 + r_lo;
    const int aoff = ar * 32 + ((s_hi ^ (ar & 3)) << 3);
    const int nloc = wn * 16 + r_lo;
    const int boff = nloc * 32 + ((s_hi ^ (nloc & 3)) << 3);

    f32x4 accL[8], accR[8];
    const f32x4 zero = {0.f, 0.f, 0.f, 0.f};
#pragma unroll
    for (int i = 0; i < 8; ++i) { accL[i] = zero; accR[i] = zero; }

    // prologue
    GL2LDS(aS0, aD0);
    GL2LDS(aS1, aD1);
    GL2LDS(wS, wD);
    __syncthreads();

    for (int kk = 0; kk < 16; ++kk) {
        const int buf = kk & 1;
        if (kk < 15) {                       // stage next tile BEFORE compute
            const int nb = (buf ^ 1);
            GL2LDS(aS0 + (kk + 1) * 32, aD0 + nb * 8192);
            GL2LDS(aS1 + (kk + 1) * 32, aD1 + nb * 8192);
            GL2LDS(wS + (kk + 1) * 32, wD + nb * 4096);
        }
        const f16* Ab = AsF + buf * 8192;
        const f16* Wb = WsF + buf * 4096;
        f16x8 bL = *(const f16x8*)(Wb + boff);
        f16x8 bR = *(const f16x8*)(Wb + 2048 + boff);
#pragma unroll
        for (int i = 0; i < 8; ++i) {
            f16x8 a = *(const f16x8*)(Ab + i * 1024 + aoff);
            accL[i] = MFMA_F16(a, bL, accL[i]);
            accR[i] = MFMA_F16(a, bR, accR[i]);
        }
        __syncthreads();
    }

    // epilogue: bias + Cl(3,0) geometric product -> gp f16 in d_out
    const int n_g = n0 + nloc;
    const float blv = bl_p[n_g], brv = br_p[n_g];
#pragma unroll
    for (int rr = 0; rr < 4; ++rr) {
        const int b_g = b0 + wb * 16 + s_hi * 4 + rr;
        float Lv[8], Rv[8];
#pragma unroll
        for (int i = 0; i < 8; ++i) { Lv[i] = accL[i][rr]; Rv[i] = accR[i][rr]; }
        Lv[0] += blv; Rv[0] += brv;
        float g[8];
        g[0] = Lv[0]*Rv[0]+Lv[1]*Rv[1]+Lv[2]*Rv[2]+Lv[3]*Rv[3]-Lv[4]*Rv[4]-Lv[5]*Rv[5]-Lv[6]*Rv[6]-Lv[7]*Rv[7];
        g[1] = Lv[0]*Rv[1]+Lv[1]*Rv[0]-Lv[2]*Rv[4]-Lv[3]*Rv[5]+Lv[4]*Rv[2]+Lv[5]*Rv[3]-Lv[6]*Rv[7]-Lv[7]*Rv[6];
        g[2] = Lv[0]*Rv[2]+Lv[1]*Rv[4]+Lv[2]*Rv[0]-Lv[3]*Rv[6]-Lv[4]*Rv[1]+Lv[5]*Rv[7]+Lv[6]*Rv[3]+Lv[7]*Rv[5];
        g[3] = Lv[0]*Rv[3]+Lv[1]*Rv[5]+Lv[2]*Rv[6]+Lv[3]*Rv[0]-Lv[4]*Rv[7]-Lv[5]*Rv[1]-Lv[6]*Rv[2]-Lv[7]*Rv[4];
        g[4] = Lv[0]*Rv[4]+Lv[1]*Rv[2]-Lv[2]*Rv[1]+Lv[3]*Rv[7]+Lv[4]*Rv[0]-Lv[5]*Rv[6]+Lv[6]*Rv[5]+Lv[7]*Rv[3];
        g[5] = Lv[0]*Rv[5]+Lv[1]*Rv[3]-Lv[2]*Rv[7]-Lv[3]*Rv[1]+Lv[4]*Rv[6]+Lv[5]*Rv[0]-Lv[6]*Rv[4]-Lv[7]*Rv[2];
        g[6] = Lv[0]*Rv[6]+Lv[1]*Rv[7]+Lv[2]*Rv[3]-Lv[3]*Rv[2]-Lv[4]*Rv[5]+Lv[5]*Rv[4]+Lv[6]*Rv[0]+Lv[7]*Rv[1];
        g[7] = Lv[0]*Rv[7]+Lv[1]*Rv[6]-Lv[2]*Rv[5]+Lv[3]*Rv[4]+Lv[4]*Rv[3]-Lv[5]*Rv[2]+Lv[6]*Rv[1]+Lv[7]*Rv[0];
        char* dst = gp_out + (size_t)b_g * 16384 + (size_t)n_g * 2;
#pragma unroll
        for (int i = 0; i < 8; ++i) *(f16*)(dst + (size_t)i * 1024) = (f16)g[i];
    }
}

// ---------------------------------------------------------------------------
// k2: out = gp @ W_out^T + bias, MVLayerNorm, scale. Block 16 b x 512 ch,
// 16 waves, K=512. Staging via global_load_lds; compute identical to round-2.
// Reads gp only from its own batch regions of d_out; writes fp32 after.
// ---------------------------------------------------------------------------
__global__ __launch_bounds__(1024, 4) void k2(
    const char* gp_in, const f16* __restrict__ wo,
    const float* __restrict__ bo_p, const float* __restrict__ an_p,
    float* outp)
{
    __shared__ __align__(16) f16 AsF[2 * 4096];    // [buf][blade][row16][k32] 16KB
    __shared__ __align__(16) f16 BsF[2 * 16384];   // [buf][n512][k32]         64KB
    __shared__ float red[16][16];

    const int b0 = blockIdx.x * 16;
    const int tid = threadIdx.x, lane = tid & 63, wv = tid >> 6;   // wv 0..15
    const int r_lo = lane & 15, s_hi = lane >> 4;

    // --- staging sources ---
    // A (waves 0..7): g = tid -> (blade, row, grp)
    const int gA = tid;
    const int abl = gA >> 6, arw = (gA >> 2) & 15, agp = (gA & 3) ^ (arw & 3);
    const char* aS = gp_in + (size_t)(b0 + arw) * 16384 + abl * 1024 + agp * 16;
    // B call j: g = j*1024 + tid -> (n, grp)
    const int gB0 = tid, gB1 = tid + 1024;
    const int bn0 = gB0 >> 2, bg0 = (gB0 & 3) ^ (bn0 & 3);
    const int bn1 = gB1 >> 2, bg1 = (gB1 & 3) ^ (bn1 & 3);
    const f16* bS0 = wo + (size_t)bn0 * 512 + bg0 * 8;
    const f16* bS1 = wo + (size_t)bn1 * 512 + bg1 * 8;

    f16* aD  = AsF + wv * 512;            // only wv<8 uses it
    f16* bD0 = BsF + wv * 512;
    f16* bD1 = BsF + 8192 + wv * 512;

    // --- compute-side offsets (round-2 image) ---
    const int aoff = r_lo * 32 + ((s_hi ^ (r_lo & 3)) << 3);
    const int nl0 = wv * 32 + r_lo, nl1 = nl0 + 16;
    const int boff0 = nl0 * 32 + ((s_hi ^ (nl0 & 3)) << 3);
    const int boff1 = nl1 * 32 + ((s_hi ^ (nl1 & 3)) << 3);

    f32x4 acc[2][8];
    const f32x4 zero = {0.f, 0.f, 0.f, 0.f};
#pragma unroll
    for (int st = 0; st < 2; ++st)
#pragma unroll
        for (int i = 0; i < 8; ++i) acc[st][i] = zero;

    // prologue
    if (wv < 8) GL2LDS(aS, aD);
    GL2LDS(bS0, bD0);
    GL2LDS(bS1, bD1);
    __syncthreads();

    for (int kk = 0; kk < 16; ++kk) {
        const int buf = kk & 1;
        if (kk < 15) {
            const int nb = buf ^ 1;
            if (wv < 8) GL2LDS(aS + (kk + 1) * 64, aD + nb * 4096);
            GL2LDS(bS0 + (kk + 1) * 32, bD0 + nb * 16384);
            GL2LDS(bS1 + (kk + 1) * 32, bD1 + nb * 16384);
        }
        const f16* Ab = AsF + buf * 4096;
        const f16* Bb = BsF + buf * 16384;
        f16x8 bf0 = *(const f16x8*)(Bb + boff0);
        f16x8 bf1 = *(const f16x8*)(Bb + boff1);
#pragma unroll
        for (int i = 0; i < 8; ++i) {
            f16x8 a = *(const f16x8*)(Ab + i * 512 + aoff);
            acc[0][i] = MFMA_F16(a, bf0, acc[0][i]);
            acc[1][i] = MFMA_F16(a, bf1, acc[1][i]);
        }
        __syncthreads();
    }

    const float bo0 = bo_p[nl0], bo1 = bo_p[nl1];
    const float an0 = an_p[nl0], an1 = an_p[nl1];

    float partial[4];
#pragma unroll
    for (int rr = 0; rr < 4; ++rr) {
        float o = acc[0][0][rr] + bo0;
        float ss = o * o;
#pragma unroll
        for (int i = 1; i < 8; ++i) ss += acc[0][i][rr] * acc[0][i][rr];
        float s = sqrtf(ss);
        o = acc[1][0][rr] + bo1;
        ss = o * o;
#pragma unroll
        for (int i = 1; i < 8; ++i) ss += acc[1][i][rr] * acc[1][i][rr];
        partial[rr] = s + sqrtf(ss);
    }
#pragma unroll
    for (int off = 1; off < 16; off <<= 1)
#pragma unroll
        for (int rr = 0; rr < 4; ++rr) partial[rr] += __shfl_xor(partial[rr], off);
    if (r_lo == 0)
#pragma unroll
        for (int rr = 0; rr < 4; ++rr) red[s_hi * 4 + rr][wv] = partial[rr];
    __syncthreads();   // also: all gp reads done before fp32 stores below

#pragma unroll
    for (int rr = 0; rr < 4; ++rr) {
        float tot = 0.f;
#pragma unroll
        for (int w = 0; w < 16; ++w) tot += red[s_hi * 4 + rr][w];
        const float inv = 1.0f / (tot * (1.0f / 512.0f) + 1e-6f);
        const float sc0 = an0 * inv, sc1 = an1 * inv;
        const int b_g = b0 + s_hi * 4 + rr;
        float* dst = outp + (size_t)b_g * 4096;
        f32x4 v;
        v[0] = (acc[0][0][rr] + bo0) * sc0;
        v[1] = acc[0][1][rr] * sc0; v[2] = acc[0][2][rr] * sc0; v[3] = acc[0][3][rr] * sc0;
        *(f32x4*)(dst + (size_t)nl0 * 8) = v;
        v[0] = acc[0][4][rr] * sc0; v[1] = acc[0][5][rr] * sc0;
        v[2] = acc[0][6][rr] * sc0; v[3] = acc[0][7][rr] * sc0;
        *(f32x4*)(dst + (size_t)nl0 * 8 + 4) = v;
        v[0] = (acc[1][0][rr] + bo1) * sc1;
        v[1] = acc[1][1][rr] * sc1; v[2] = acc[1][2][rr] * sc1; v[3] = acc[1][3][rr] * sc1;
        *(f32x4*)(dst + (size_t)nl1 * 8) = v;
        v[0] = acc[1][4][rr] * sc1; v[1] = acc[1][5][rr] * sc1;
        v[2] = acc[1][6][rr] * sc1; v[3] = acc[1][7][rr] * sc1;
        *(f32x4*)(dst + (size_t)nl1 * 8 + 4) = v;
    }
}

// ---------------------------------------------------------------------------
extern "C" void kernel_launch(void* const* d_in, const int* in_sizes, int n_in,
                              void* d_out, int out_size, void* d_ws, size_t ws_size,
                              hipStream_t stream) {
    const float* x  = (const float*)d_in[0];
    const float* wl = (const float*)d_in[1];
    const float* bl = (const float*)d_in[2];
    const float* wr = (const float*)d_in[3];
    const float* br = (const float*)d_in[4];
    const float* wo = (const float*)d_in[5];
    const float* bo = (const float*)d_in[6];
    const float* an = (const float*)d_in[7];
    f16* wf = (f16*)d_ws;
    f16* xt = wf + (1 << 20);   // byte offset 2MB; needs 130MB (confirmed in R3)

    hipLaunchKernelGGL(k0w, dim3(1024), dim3(256), 0, stream, wl, wr, wo, wf);
    hipLaunchKernelGGL(k0x, dim3(8192), dim3(256), 0, stream, x, xt);
    hipLaunchKernelGGL(k1,  dim3(4096), dim3(512), 0, stream, xt, wf, bl, br, (char*)d_out);
    hipLaunchKernelGGL(k2,  dim3(1024), dim3(1024), 0, stream,
                       (const char*)d_out, wf + 524288, bo, an, (float*)d_out);
}

// Round 5
// 447.030 us; speedup vs baseline: 1.5543x; 1.0142x over previous
//
#include <hip/hip_runtime.h>
#include <cstdint>
#include <cstddef>

typedef _Float16 f16;
typedef __attribute__((ext_vector_type(8))) _Float16 f16x8;
typedef __attribute__((ext_vector_type(4))) _Float16 f16x4;
typedef __attribute__((ext_vector_type(4))) float f32x4;

#define MFMA_F16(a, b, c) __builtin_amdgcn_mfma_f32_16x16x32_f16((a), (b), (c), 0, 0, 0)

// global -> LDS direct, 16B per lane. LDS dest = WAVE base (HW adds lane*16);
// global src per-lane (swizzle baked into source address).
#define GL2LDS(gsrc, ldst)                                                  \
    __builtin_amdgcn_global_load_lds(                                        \
        (const __attribute__((address_space(1))) void*)(gsrc),               \
        (__attribute__((address_space(3))) void*)(ldst), 16, 0, 0)

// Bank swizzle: rows are 64B (32 f16); slot = s ^ ((row>>1)&3) so each
// contiguous-8-lane group covers all 32 banks (even rows -> 4 distinct low
// slots, odd rows -> 4 distinct high slots).  f(row)=(row&3) was a 2-way
// conflict (rows r, r+4 collide) = the measured 2.1e7 SQ_LDS_BANK_CONFLICT.
#define SWZ(row) (((row) >> 1) & 3)

// ws layout (f16 elems): [0,262144) W_L | [262144,524288) W_R |
//   [524288,786432) W_out | xt at elem 1<<20: 8 blade planes of [16384][512].
// gp (f16) in d_out: batch b at byte b*16384, blade i at +i*1024, ch n at +2n.

// ---------------------------------------------------------------------------
// k0: blocks 0..8191 transpose x [b][m][i] f32 -> xt [i][b][m] f16;
//     blocks 8192..9215 convert the three weight matrices.
// ---------------------------------------------------------------------------
__global__ __launch_bounds__(256) void k0(const float* __restrict__ x,
                                          const float* __restrict__ wl,
                                          const float* __restrict__ wr,
                                          const float* __restrict__ wo,
                                          f16* __restrict__ wdst,
                                          f16* __restrict__ xt) {
    const int bid = blockIdx.x;
    if (bid >= 8192) {
        int i = (bid - 8192) * 256 + threadIdx.x;
        wdst[i]          = (f16)wl[i];
        wdst[262144 + i] = (f16)wr[i];
        wdst[524288 + i] = (f16)wo[i];
        return;
    }
    const int b = (bid >> 1) * 4 + (threadIdx.x >> 6);
    const int m = (bid & 1) * 256 + (threadIdx.x & 63) * 4;
    const float* src = x + ((size_t)b * 512 + m) * 8;
    f32x4 v[8];
#pragma unroll
    for (int u = 0; u < 8; ++u) v[u] = *(const f32x4*)(src + u * 4);
#pragma unroll
    for (int i = 0; i < 8; ++i) {
        f16x4 w;
#pragma unroll
        for (int j = 0; j < 4; ++j) w[j] = (f16)v[j * 2 + (i >> 2)][i & 3];
        *(f16x4*)(xt + (size_t)i * 8388608 + (size_t)b * 512 + m) = w;
    }
}

// ---------------------------------------------------------------------------
// k1: vec_L/vec_R GEMMs + geometric product. Block 32 b x 64 ch, BK=32,
// 8 waves (16x16, L+R). All staging via global_load_lds(16B), sources
// pre-swizzled with SWZ; reads use the same involution.
// ---------------------------------------------------------------------------
__global__ __launch_bounds__(512, 4) void k1(
    const f16* __restrict__ xt, const f16* __restrict__ wf,
    const float* __restrict__ bl_p, const float* __restrict__ br_p,
    char* gp_out)
{
    __shared__ __align__(16) f16 AsF[2 * 8192];   // [buf][blade][row32][k32] 32KB
    __shared__ __align__(16) f16 WsF[2 * 4096];   // [buf][side][n64][k32]    16KB

    const int L = blockIdx.x;                     // XCD-chunked swizzle
    const int xcd = L & 7, sl = L >> 3;
    const int bt = xcd * 64 + (sl >> 3), ct = sl & 7;
    const int b0 = bt * 32, n0 = ct * 64;

    const int tid = threadIdx.x, lane = tid & 63, wv = tid >> 6;
    const int wb = wv >> 2, wn = wv & 3;
    const int r_lo = lane & 15, s_hi = lane >> 4;

    // staging sources: A call j covers flat groups g=j*512+tid -> (blade,row,grp)
    const int gA0 = tid, gA1 = tid + 512;
    const int ba0 = gA0 >> 7, ra0 = (gA0 >> 2) & 31, ga0 = (gA0 & 3) ^ SWZ(ra0);
    const int ba1 = gA1 >> 7, ra1 = (gA1 >> 2) & 31, ga1 = (gA1 & 3) ^ SWZ(ra1);
    const f16* aS0 = xt + (size_t)ba0 * 8388608 + (size_t)(b0 + ra0) * 512 + ga0 * 8;
    const f16* aS1 = xt + (size_t)ba1 * 8388608 + (size_t)(b0 + ra1) * 512 + ga1 * 8;
    // W: g = tid -> (side, n, grp)
    const int side = tid >> 8, wn_ = (tid >> 2) & 63, wg = (tid & 3) ^ SWZ(wn_);
    const f16* wS = wf + (size_t)side * 262144 + (size_t)(n0 + wn_) * 512 + wg * 8;

    // wave-uniform LDS dest bases
    f16* aD0 = AsF + wv * 512;
    f16* aD1 = AsF + 4096 + wv * 512;
    f16* wD  = WsF + wv * 512;

    // compute-side LDS offsets (same involution)
    const int ar = wb * 16 + r_lo;
    const int aoff = ar * 32 + ((s_hi ^ SWZ(ar)) << 3);
    const int nloc = wn * 16 + r_lo;
    const int boff = nloc * 32 + ((s_hi ^ SWZ(nloc)) << 3);

    f32x4 accL[8], accR[8];
    const f32x4 zero = {0.f, 0.f, 0.f, 0.f};
#pragma unroll
    for (int i = 0; i < 8; ++i) { accL[i] = zero; accR[i] = zero; }

    GL2LDS(aS0, aD0);
    GL2LDS(aS1, aD1);
    GL2LDS(wS, wD);
    __syncthreads();

    for (int kk = 0; kk < 16; ++kk) {
        const int buf = kk & 1;
        if (kk < 15) {
            const int nb = (buf ^ 1);
            GL2LDS(aS0 + (kk + 1) * 32, aD0 + nb * 8192);
            GL2LDS(aS1 + (kk + 1) * 32, aD1 + nb * 8192);
            GL2LDS(wS + (kk + 1) * 32, wD + nb * 4096);
        }
        const f16* Ab = AsF + buf * 8192;
        const f16* Wb = WsF + buf * 4096;
        f16x8 bL = *(const f16x8*)(Wb + boff);
        f16x8 bR = *(const f16x8*)(Wb + 2048 + boff);
#pragma unroll
        for (int i = 0; i < 8; ++i) {
            f16x8 a = *(const f16x8*)(Ab + i * 1024 + aoff);
            accL[i] = MFMA_F16(a, bL, accL[i]);
            accR[i] = MFMA_F16(a, bR, accR[i]);
        }
        __syncthreads();
    }

    // epilogue: bias + Cl(3,0) geometric product -> gp f16 in d_out
    const int n_g = n0 + nloc;
    const float blv = bl_p[n_g], brv = br_p[n_g];
#pragma unroll
    for (int rr = 0; rr < 4; ++rr) {
        const int b_g = b0 + wb * 16 + s_hi * 4 + rr;
        float Lv[8], Rv[8];
#pragma unroll
        for (int i = 0; i < 8; ++i) { Lv[i] = accL[i][rr]; Rv[i] = accR[i][rr]; }
        Lv[0] += blv; Rv[0] += brv;
        float g[8];
        g[0] = Lv[0]*Rv[0]+Lv[1]*Rv[1]+Lv[2]*Rv[2]+Lv[3]*Rv[3]-Lv[4]*Rv[4]-Lv[5]*Rv[5]-Lv[6]*Rv[6]-Lv[7]*Rv[7];
        g[1] = Lv[0]*Rv[1]+Lv[1]*Rv[0]-Lv[2]*Rv[4]-Lv[3]*Rv[5]+Lv[4]*Rv[2]+Lv[5]*Rv[3]-Lv[6]*Rv[7]-Lv[7]*Rv[6];
        g[2] = Lv[0]*Rv[2]+Lv[1]*Rv[4]+Lv[2]*Rv[0]-Lv[3]*Rv[6]-Lv[4]*Rv[1]+Lv[5]*Rv[7]+Lv[6]*Rv[3]+Lv[7]*Rv[5];
        g[3] = Lv[0]*Rv[3]+Lv[1]*Rv[5]+Lv[2]*Rv[6]+Lv[3]*Rv[0]-Lv[4]*Rv[7]-Lv[5]*Rv[1]-Lv[6]*Rv[2]-Lv[7]*Rv[4];
        g[4] = Lv[0]*Rv[4]+Lv[1]*Rv[2]-Lv[2]*Rv[1]+Lv[3]*Rv[7]+Lv[4]*Rv[0]-Lv[5]*Rv[6]+Lv[6]*Rv[5]+Lv[7]*Rv[3];
        g[5] = Lv[0]*Rv[5]+Lv[1]*Rv[3]-Lv[2]*Rv[7]-Lv[3]*Rv[1]+Lv[4]*Rv[6]+Lv[5]*Rv[0]-Lv[6]*Rv[4]-Lv[7]*Rv[2];
        g[6] = Lv[0]*Rv[6]+Lv[1]*Rv[7]+Lv[2]*Rv[3]-Lv[3]*Rv[2]-Lv[4]*Rv[5]+Lv[5]*Rv[4]+Lv[6]*Rv[0]+Lv[7]*Rv[1];
        g[7] = Lv[0]*Rv[7]+Lv[1]*Rv[6]-Lv[2]*Rv[5]+Lv[3]*Rv[4]+Lv[4]*Rv[3]-Lv[5]*Rv[2]+Lv[6]*Rv[1]+Lv[7]*Rv[0];
        char* dst = gp_out + (size_t)b_g * 16384 + (size_t)n_g * 2;
#pragma unroll
        for (int i = 0; i < 8; ++i) *(f16*)(dst + (size_t)i * 1024) = (f16)g[i];
    }
}

// ---------------------------------------------------------------------------
// k2: out = gp @ W_out^T + bias, MVLayerNorm, scale. Block 16 b x 512 ch,
// 16 waves, K=512. Staging via global_load_lds with SWZ sources.
// ---------------------------------------------------------------------------
__global__ __launch_bounds__(1024, 4) void k2(
    const char* gp_in, const f16* __restrict__ wo,
    const float* __restrict__ bo_p, const float* __restrict__ an_p,
    float* outp)
{
    __shared__ __align__(16) f16 AsF[2 * 4096];    // [buf][blade][row16][k32] 16KB
    __shared__ __align__(16) f16 BsF[2 * 16384];   // [buf][n512][k32]         64KB
    __shared__ float red[16][16];

    const int b0 = blockIdx.x * 16;
    const int tid = threadIdx.x, lane = tid & 63, wv = tid >> 6;   // wv 0..15
    const int r_lo = lane & 15, s_hi = lane >> 4;

    // staging sources
    const int gA = tid;
    const int abl = gA >> 6, arw = (gA >> 2) & 15, agp = (gA & 3) ^ SWZ(arw);
    const char* aS = gp_in + (size_t)(b0 + arw) * 16384 + abl * 1024 + agp * 16;
    const int gB0 = tid, gB1 = tid + 1024;
    const int bn0 = gB0 >> 2, bg0 = (gB0 & 3) ^ SWZ(bn0);
    const int bn1 = gB1 >> 2, bg1 = (gB1 & 3) ^ SWZ(bn1);
    const f16* bS0 = wo + (size_t)bn0 * 512 + bg0 * 8;
    const f16* bS1 = wo + (size_t)bn1 * 512 + bg1 * 8;

    f16* aD  = AsF + wv * 512;            // only wv<8 uses it
    f16* bD0 = BsF + wv * 512;
    f16* bD1 = BsF + 8192 + wv * 512;

    // compute-side offsets
    const int aoff = r_lo * 32 + ((s_hi ^ SWZ(r_lo)) << 3);
    const int nl0 = wv * 32 + r_lo, nl1 = nl0 + 16;
    const int boff0 = nl0 * 32 + ((s_hi ^ SWZ(nl0)) << 3);
    const int boff1 = nl1 * 32 + ((s_hi ^ SWZ(nl1)) << 3);

    f32x4 acc[2][8];
    const f32x4 zero = {0.f, 0.f, 0.f, 0.f};
#pragma unroll
    for (int st = 0; st < 2; ++st)
#pragma unroll
        for (int i = 0; i < 8; ++i) acc[st][i] = zero;

    if (wv < 8) GL2LDS(aS, aD);
    GL2LDS(bS0, bD0);
    GL2LDS(bS1, bD1);
    __syncthreads();

    for (int kk = 0; kk < 16; ++kk) {
        const int buf = kk & 1;
        if (kk < 15) {
            const int nb = buf ^ 1;
            if (wv < 8) GL2LDS(aS + (kk + 1) * 64, aD + nb * 4096);
            GL2LDS(bS0 + (kk + 1) * 32, bD0 + nb * 16384);
            GL2LDS(bS1 + (kk + 1) * 32, bD1 + nb * 16384);
        }
        const f16* Ab = AsF + buf * 4096;
        const f16* Bb = BsF + buf * 16384;
        f16x8 bf0 = *(const f16x8*)(Bb + boff0);
        f16x8 bf1 = *(const f16x8*)(Bb + boff1);
#pragma unroll
        for (int i = 0; i < 8; ++i) {
            f16x8 a = *(const f16x8*)(Ab + i * 512 + aoff);
            acc[0][i] = MFMA_F16(a, bf0, acc[0][i]);
            acc[1][i] = MFMA_F16(a, bf1, acc[1][i]);
        }
        __syncthreads();
    }

    const float bo0 = bo_p[nl0], bo1 = bo_p[nl1];
    const float an0 = an_p[nl0], an1 = an_p[nl1];

    float partial[4];
#pragma unroll
    for (int rr = 0; rr < 4; ++rr) {
        float o = acc[0][0][rr] + bo0;
        float ss = o * o;
#pragma unroll
        for (int i = 1; i < 8; ++i) ss += acc[0][i][rr] * acc[0][i][rr];
        float s = sqrtf(ss);
        o = acc[1][0][rr] + bo1;
        ss = o * o;
#pragma unroll
        for (int i = 1; i < 8; ++i) ss += acc[1][i][rr] * acc[1][i][rr];
        partial[rr] = s + sqrtf(ss);
    }
#pragma unroll
    for (int off = 1; off < 16; off <<= 1)
#pragma unroll
        for (int rr = 0; rr < 4; ++rr) partial[rr] += __shfl_xor(partial[rr], off);
    if (r_lo == 0)
#pragma unroll
        for (int rr = 0; rr < 4; ++rr) red[s_hi * 4 + rr][wv] = partial[rr];
    __syncthreads();   // also: all gp reads done before fp32 stores below

#pragma unroll
    for (int rr = 0; rr < 4; ++rr) {
        float tot = 0.f;
#pragma unroll
        for (int w = 0; w < 16; ++w) tot += red[s_hi * 4 + rr][w];
        const float inv = 1.0f / (tot * (1.0f / 512.0f) + 1e-6f);
        const float sc0 = an0 * inv, sc1 = an1 * inv;
        const int b_g = b0 + s_hi * 4 + rr;
        float* dst = outp + (size_t)b_g * 4096;
        f32x4 v;
        v[0] = (acc[0][0][rr] + bo0) * sc0;
        v[1] = acc[0][1][rr] * sc0; v[2] = acc[0][2][rr] * sc0; v[3] = acc[0][3][rr] * sc0;
        *(f32x4*)(dst + (size_t)nl0 * 8) = v;
        v[0] = acc[0][4][rr] * sc0; v[1] = acc[0][5][rr] * sc0;
        v[2] = acc[0][6][rr] * sc0; v[3] = acc[0][7][rr] * sc0;
        *(f32x4*)(dst + (size_t)nl0 * 8 + 4) = v;
        v[0] = (acc[1][0][rr] + bo1) * sc1;
        v[1] = acc[1][1][rr] * sc1; v[2] = acc[1][2][rr] * sc1; v[3] = acc[1][3][rr] * sc1;
        *(f32x4*)(dst + (size_t)nl1 * 8) = v;
        v[0] = acc[1][4][rr] * sc1; v[1] = acc[1][5][rr] * sc1;
        v[2] = acc[1][6][rr] * sc1; v[3] = acc[1][7][rr] * sc1;
        *(f32x4*)(dst + (size_t)nl1 * 8 + 4) = v;
    }
}

// ---------------------------------------------------------------------------
extern "C" void kernel_launch(void* const* d_in, const int* in_sizes, int n_in,
                              void* d_out, int out_size, void* d_ws, size_t ws_size,
                              hipStream_t stream) {
    const float* x  = (const float*)d_in[0];
    const float* wl = (const float*)d_in[1];
    const float* bl = (const float*)d_in[2];
    const float* wr = (const float*)d_in[3];
    const float* br = (const float*)d_in[4];
    const float* wo = (const float*)d_in[5];
    const float* bo = (const float*)d_in[6];
    const float* an = (const float*)d_in[7];
    f16* wf = (f16*)d_ws;
    f16* xt = wf + (1 << 20);   // byte offset 2MB; ws >= 130MB (confirmed R3)

    hipLaunchKernelGGL(k0, dim3(9216), dim3(256), 0, stream, x, wl, wr, wo, wf, xt);
    hipLaunchKernelGGL(k1, dim3(4096), dim3(512), 0, stream, xt, wf, bl, br, (char*)d_out);
    hipLaunchKernelGGL(k2, dim3(1024), dim3(1024), 0, stream,
                       (const char*)d_out, wf + 524288, bo, an, (float*)d_out);
}

// Round 6
// 432.361 us; speedup vs baseline: 1.6070x; 1.0339x over previous
//
#include <hip/hip_runtime.h>
#include <cstdint>
#include <cstddef>

typedef _Float16 f16;
typedef __attribute__((ext_vector_type(8))) _Float16 f16x8;
typedef __attribute__((ext_vector_type(4))) _Float16 f16x4;
typedef __attribute__((ext_vector_type(4))) float f32x4;

#define MFMA_F16(a, b, c) __builtin_amdgcn_mfma_f32_16x16x32_f16((a), (b), (c), 0, 0, 0)

#define GL2LDS(gsrc, ldst)                                                  \
    __builtin_amdgcn_global_load_lds(                                        \
        (const __attribute__((address_space(1))) void*)(gsrc),               \
        (__attribute__((address_space(3))) void*)(ldst), 16, 0, 0)

// counted waits + raw barrier (T3/T4: loads stay in flight ACROSS barriers)
#define WAITV(n) asm volatile("s_waitcnt vmcnt(" #n ")" ::: "memory")
#define BAR() __builtin_amdgcn_s_barrier()

// bank swizzle (verified R5: conflicts 2.1e7 -> 0)
#define SWZ(row) (((row) >> 1) & 3)

// ws layout (f16 elems): [0,262144) W_L | [262144,524288) W_R |
//   [524288,786432) W_out | xt at elem 1<<20: 8 blade planes of [16384][512].
// gp (f16) in d_out: batch b at byte b*16384, blade i at +i*1024, ch n at +2n.

// ---------------------------------------------------------------------------
// k0: blocks 0..8191 transpose x [b][m][i] f32 -> xt [i][b][m] f16;
//     blocks 8192..9215 convert the three weight matrices.
// ---------------------------------------------------------------------------
__global__ __launch_bounds__(256) void k0(const float* __restrict__ x,
                                          const float* __restrict__ wl,
                                          const float* __restrict__ wr,
                                          const float* __restrict__ wo,
                                          f16* __restrict__ wdst,
                                          f16* __restrict__ xt) {
    const int bid = blockIdx.x;
    if (bid >= 8192) {
        int i = (bid - 8192) * 256 + threadIdx.x;
        wdst[i]          = (f16)wl[i];
        wdst[262144 + i] = (f16)wr[i];
        wdst[524288 + i] = (f16)wo[i];
        return;
    }
    const int b = (bid >> 1) * 4 + (threadIdx.x >> 6);
    const int m = (bid & 1) * 256 + (threadIdx.x & 63) * 4;
    const float* src = x + ((size_t)b * 512 + m) * 8;
    f32x4 v[8];
#pragma unroll
    for (int u = 0; u < 8; ++u) v[u] = *(const f32x4*)(src + u * 4);
#pragma unroll
    for (int i = 0; i < 8; ++i) {
        f16x4 w;
#pragma unroll
        for (int j = 0; j < 4; ++j) w[j] = (f16)v[j * 2 + (i >> 2)][i & 3];
        *(f16x4*)(xt + (size_t)i * 8388608 + (size_t)b * 512 + m) = w;
    }
}

// ---------------------------------------------------------------------------
// k1: vec_L/vec_R GEMMs + geometric product. Block 32 b x 64 ch, BK=32,
// 8 waves (16x16, L+R). 3-deep pipeline: 3 LDS buffers, 9 loads in flight,
// steady-state wait vmcnt(6) -- never drains to 0 in the main loop.
// ---------------------------------------------------------------------------
__global__ __launch_bounds__(512, 2) void k1(
    const f16* __restrict__ xt, const f16* __restrict__ wf,
    const float* __restrict__ bl_p, const float* __restrict__ br_p,
    char* gp_out)
{
    __shared__ __align__(16) f16 AsF[3 * 8192];   // [buf][blade][row32][k32] 48KB
    __shared__ __align__(16) f16 WsF[3 * 4096];   // [buf][side][n64][k32]    24KB

    const int L = blockIdx.x;                     // XCD-chunked swizzle
    const int xcd = L & 7, sl = L >> 3;
    const int bt = xcd * 64 + (sl >> 3), ct = sl & 7;
    const int b0 = bt * 32, n0 = ct * 64;

    const int tid = threadIdx.x, lane = tid & 63, wv = tid >> 6;
    const int wb = wv >> 2, wn = wv & 3;
    const int r_lo = lane & 15, s_hi = lane >> 4;

    // staging sources (pre-swizzled)
    const int gA0 = tid, gA1 = tid + 512;
    const int ba0 = gA0 >> 7, ra0 = (gA0 >> 2) & 31, ga0 = (gA0 & 3) ^ SWZ(ra0);
    const int ba1 = gA1 >> 7, ra1 = (gA1 >> 2) & 31, ga1 = (gA1 & 3) ^ SWZ(ra1);
    const f16* aS0 = xt + (size_t)ba0 * 8388608 + (size_t)(b0 + ra0) * 512 + ga0 * 8;
    const f16* aS1 = xt + (size_t)ba1 * 8388608 + (size_t)(b0 + ra1) * 512 + ga1 * 8;
    const int side = tid >> 8, wn_ = (tid >> 2) & 63, wg = (tid & 3) ^ SWZ(wn_);
    const f16* wS = wf + (size_t)side * 262144 + (size_t)(n0 + wn_) * 512 + wg * 8;

    // wave-uniform LDS dest bases (buf 0)
    f16* aD0 = AsF + wv * 512;
    f16* aD1 = AsF + 4096 + wv * 512;
    f16* wD  = WsF + wv * 512;

    // compute-side offsets
    const int ar = wb * 16 + r_lo;
    const int aoff = ar * 32 + ((s_hi ^ SWZ(ar)) << 3);
    const int nloc = wn * 16 + r_lo;
    const int boff = nloc * 32 + ((s_hi ^ SWZ(nloc)) << 3);

    f32x4 accL[8], accR[8];
    const f32x4 zero = {0.f, 0.f, 0.f, 0.f};
#pragma unroll
    for (int i = 0; i < 8; ++i) { accL[i] = zero; accR[i] = zero; }

    auto stage = [&](int kt, int buf) {
        GL2LDS(aS0 + kt * 32, aD0 + buf * 8192);
        GL2LDS(aS1 + kt * 32, aD1 + buf * 8192);
        GL2LDS(wS + kt * 32, wD + buf * 4096);
    };

    stage(0, 0);
    stage(1, 1);

#pragma unroll
    for (int kk = 0; kk < 16; ++kk) {
        if (kk + 2 < 16) stage(kk + 2, (kk + 2) % 3);
        if (kk <= 13)      { WAITV(6); }
        else if (kk == 14) { WAITV(3); }
        else               { WAITV(0); }
        BAR();
        const f16* Ab = AsF + (kk % 3) * 8192;
        const f16* Wb = WsF + (kk % 3) * 4096;
        f16x8 bL = *(const f16x8*)(Wb + boff);
        f16x8 bR = *(const f16x8*)(Wb + 2048 + boff);
#pragma unroll
        for (int i = 0; i < 8; ++i) {
            f16x8 a = *(const f16x8*)(Ab + i * 1024 + aoff);
            accL[i] = MFMA_F16(a, bL, accL[i]);
            accR[i] = MFMA_F16(a, bR, accR[i]);
        }
        BAR();   // all reads of buf kk%3 done before stage(kk+3) overwrites
    }

    // epilogue: bias + Cl(3,0) geometric product -> gp f16 in d_out
    const int n_g = n0 + nloc;
    const float blv = bl_p[n_g], brv = br_p[n_g];
#pragma unroll
    for (int rr = 0; rr < 4; ++rr) {
        const int b_g = b0 + wb * 16 + s_hi * 4 + rr;
        float Lv[8], Rv[8];
#pragma unroll
        for (int i = 0; i < 8; ++i) { Lv[i] = accL[i][rr]; Rv[i] = accR[i][rr]; }
        Lv[0] += blv; Rv[0] += brv;
        float g[8];
        g[0] = Lv[0]*Rv[0]+Lv[1]*Rv[1]+Lv[2]*Rv[2]+Lv[3]*Rv[3]-Lv[4]*Rv[4]-Lv[5]*Rv[5]-Lv[6]*Rv[6]-Lv[7]*Rv[7];
        g[1] = Lv[0]*Rv[1]+Lv[1]*Rv[0]-Lv[2]*Rv[4]-Lv[3]*Rv[5]+Lv[4]*Rv[2]+Lv[5]*Rv[3]-Lv[6]*Rv[7]-Lv[7]*Rv[6];
        g[2] = Lv[0]*Rv[2]+Lv[1]*Rv[4]+Lv[2]*Rv[0]-Lv[3]*Rv[6]-Lv[4]*Rv[1]+Lv[5]*Rv[7]+Lv[6]*Rv[3]+Lv[7]*Rv[5];
        g[3] = Lv[0]*Rv[3]+Lv[1]*Rv[5]+Lv[2]*Rv[6]+Lv[3]*Rv[0]-Lv[4]*Rv[7]-Lv[5]*Rv[1]-Lv[6]*Rv[2]-Lv[7]*Rv[4];
        g[4] = Lv[0]*Rv[4]+Lv[1]*Rv[2]-Lv[2]*Rv[1]+Lv[3]*Rv[7]+Lv[4]*Rv[0]-Lv[5]*Rv[6]+Lv[6]*Rv[5]+Lv[7]*Rv[3];
        g[5] = Lv[0]*Rv[5]+Lv[1]*Rv[3]-Lv[2]*Rv[7]-Lv[3]*Rv[1]+Lv[4]*Rv[6]+Lv[5]*Rv[0]-Lv[6]*Rv[4]-Lv[7]*Rv[2];
        g[6] = Lv[0]*Rv[6]+Lv[1]*Rv[7]+Lv[2]*Rv[3]-Lv[3]*Rv[2]-Lv[4]*Rv[5]+Lv[5]*Rv[4]+Lv[6]*Rv[0]+Lv[7]*Rv[1];
        g[7] = Lv[0]*Rv[7]+Lv[1]*Rv[6]-Lv[2]*Rv[5]+Lv[3]*Rv[4]+Lv[4]*Rv[3]-Lv[5]*Rv[2]+Lv[6]*Rv[1]+Lv[7]*Rv[0];
        char* dst = gp_out + (size_t)b_g * 16384 + (size_t)n_g * 2;
#pragma unroll
        for (int i = 0; i < 8; ++i) *(f16*)(dst + (size_t)i * 1024) = (f16)g[i];
    }
}

// ---------------------------------------------------------------------------
// k2: out = gp @ W_out^T + bias, MVLayerNorm, scale.
// Block 16 b x 512 ch, 8 waves, wave tile 16x64 (acc[4][8]) -- halves the
// A ds_read redundancy vs 16 waves. 3-deep pipeline, 5 loads/tile,
// steady wait vmcnt(10).
// ---------------------------------------------------------------------------
__global__ __launch_bounds__(512, 1) void k2(
    const char* gp_in, const f16* __restrict__ wo,
    const float* __restrict__ bo_p, const float* __restrict__ an_p,
    float* outp)
{
    __shared__ __align__(16) f16 AsF[3 * 4096];    // [buf][blade][row16][k32] 24KB
    __shared__ __align__(16) f16 BsF[3 * 16384];   // [buf][n512][k32]         96KB
    __shared__ float red[16][8];

    const int b0 = blockIdx.x * 16;
    const int tid = threadIdx.x, lane = tid & 63, wv = tid >> 6;   // wv 0..7
    const int r_lo = lane & 15, s_hi = lane >> 4;

    // staging sources: A = 8KB/tile = 1 call (512 lanes x 16B)
    const int abl = tid >> 6, arw = (tid >> 2) & 15, agp = (tid & 3) ^ SWZ(arw);
    const char* aS = gp_in + (size_t)(b0 + arw) * 16384 + abl * 1024 + agp * 16;
    // B = 32KB/tile = 4 calls; call j covers rows [j*128, j*128+128)
    const f16* bS[4];
#pragma unroll
    for (int j = 0; j < 4; ++j) {
        const int g = j * 512 + tid;
        const int bn = g >> 2, bg = (g & 3) ^ SWZ(bn);
        bS[j] = wo + (size_t)bn * 512 + bg * 8;
    }

    f16* aD = AsF + wv * 512;
    f16* bD = BsF + wv * 512;   // call j adds j*4096

    // compute-side offsets
    const int aoff = r_lo * 32 + ((s_hi ^ SWZ(r_lo)) << 3);
    int boffs[4];
#pragma unroll
    for (int t = 0; t < 4; ++t) {
        const int nl = wv * 64 + t * 16 + r_lo;
        boffs[t] = nl * 32 + ((s_hi ^ SWZ(nl)) << 3);
    }

    f32x4 acc[4][8];
    const f32x4 zero = {0.f, 0.f, 0.f, 0.f};
#pragma unroll
    for (int t = 0; t < 4; ++t)
#pragma unroll
        for (int i = 0; i < 8; ++i) acc[t][i] = zero;

    auto stage = [&](int kt, int buf) {
        GL2LDS(aS + kt * 64, aD + buf * 4096);
#pragma unroll
        for (int j = 0; j < 4; ++j)
            GL2LDS(bS[j] + kt * 32, bD + buf * 16384 + j * 4096);
    };

    stage(0, 0);
    stage(1, 1);

#pragma unroll
    for (int kk = 0; kk < 16; ++kk) {
        if (kk + 2 < 16) stage(kk + 2, (kk + 2) % 3);
        if (kk <= 13)      { WAITV(10); }
        else if (kk == 14) { WAITV(5); }
        else               { WAITV(0); }
        BAR();
        const f16* Ab = AsF + (kk % 3) * 4096;
        const f16* Bb = BsF + (kk % 3) * 16384;
        f16x8 bf[4];
#pragma unroll
        for (int t = 0; t < 4; ++t) bf[t] = *(const f16x8*)(Bb + boffs[t]);
#pragma unroll
        for (int i = 0; i < 8; ++i) {
            f16x8 a = *(const f16x8*)(Ab + i * 512 + aoff);
            acc[0][i] = MFMA_F16(a, bf[0], acc[0][i]);
            acc[1][i] = MFMA_F16(a, bf[1], acc[1][i]);
            acc[2][i] = MFMA_F16(a, bf[2], acc[2][i]);
            acc[3][i] = MFMA_F16(a, bf[3], acc[3][i]);
        }
        BAR();
    }

    float bo_t[4], an_t[4];
#pragma unroll
    for (int t = 0; t < 4; ++t) {
        const int c = wv * 64 + t * 16 + r_lo;
        bo_t[t] = bo_p[c]; an_t[t] = an_p[c];
    }

    // per-(batch,channel) multivector norms over this lane's 4 channels
    float partial[4];
#pragma unroll
    for (int rr = 0; rr < 4; ++rr) {
        float sum = 0.f;
#pragma unroll
        for (int t = 0; t < 4; ++t) {
            float o = acc[t][0][rr] + bo_t[t];
            float ss = o * o;
#pragma unroll
            for (int i = 1; i < 8; ++i) ss += acc[t][i][rr] * acc[t][i][rr];
            sum += sqrtf(ss);
        }
        partial[rr] = sum;
    }
#pragma unroll
    for (int off = 1; off < 16; off <<= 1)
#pragma unroll
        for (int rr = 0; rr < 4; ++rr) partial[rr] += __shfl_xor(partial[rr], off);
    if (r_lo == 0)
#pragma unroll
        for (int rr = 0; rr < 4; ++rr) red[s_hi * 4 + rr][wv] = partial[rr];
    __syncthreads();

#pragma unroll
    for (int rr = 0; rr < 4; ++rr) {
        float tot = 0.f;
#pragma unroll
        for (int w = 0; w < 8; ++w) tot += red[s_hi * 4 + rr][w];
        const float inv = 1.0f / (tot * (1.0f / 512.0f) + 1e-6f);
        const int b_g = b0 + s_hi * 4 + rr;
        float* dst = outp + (size_t)b_g * 4096;
#pragma unroll
        for (int t = 0; t < 4; ++t) {
            const float sc = an_t[t] * inv;
            const int c = wv * 64 + t * 16 + r_lo;
            f32x4 v0, v1;
            v0[0] = (acc[t][0][rr] + bo_t[t]) * sc;
            v0[1] = acc[t][1][rr] * sc; v0[2] = acc[t][2][rr] * sc; v0[3] = acc[t][3][rr] * sc;
            v1[0] = acc[t][4][rr] * sc; v1[1] = acc[t][5][rr] * sc;
            v1[2] = acc[t][6][rr] * sc; v1[3] = acc[t][7][rr] * sc;
            *(f32x4*)(dst + (size_t)c * 8) = v0;
            *(f32x4*)(dst + (size_t)c * 8 + 4) = v1;
        }
    }
}

// ---------------------------------------------------------------------------
extern "C" void kernel_launch(void* const* d_in, const int* in_sizes, int n_in,
                              void* d_out, int out_size, void* d_ws, size_t ws_size,
                              hipStream_t stream) {
    const float* x  = (const float*)d_in[0];
    const float* wl = (const float*)d_in[1];
    const float* bl = (const float*)d_in[2];
    const float* wr = (const float*)d_in[3];
    const float* br = (const float*)d_in[4];
    const float* wo = (const float*)d_in[5];
    const float* bo = (const float*)d_in[6];
    const float* an = (const float*)d_in[7];
    f16* wf = (f16*)d_ws;
    f16* xt = wf + (1 << 20);   // byte offset 2MB; ws >= 130MB (confirmed R3)

    hipLaunchKernelGGL(k0, dim3(9216), dim3(256), 0, stream, x, wl, wr, wo, wf, xt);
    hipLaunchKernelGGL(k1, dim3(4096), dim3(512), 0, stream, xt, wf, bl, br, (char*)d_out);
    hipLaunchKernelGGL(k2, dim3(1024), dim3(512), 0, stream,
                       (const char*)d_out, wf + 524288, bo, an, (float*)d_out);
}